// Round 1
// 659.307 us; speedup vs baseline: 1.0342x; 1.0342x over previous
//
#include <hip/hip_runtime.h>
#include <hip/hip_bf16.h>

#define S_LEN 128
#define B_SZ  32
#define VOCAB 32000
#define EMB   32
#define HID   8
#define NROWS 4096   // S_LEN * B_SZ

typedef float v2f __attribute__((ext_vector_type(2)));
typedef float v4f __attribute__((ext_vector_type(4)));

#if defined(__has_builtin) && __has_builtin(__builtin_elementwise_fma)
__device__ __forceinline__ v2f fma2(v2f a, v2f b, v2f c) {
    return __builtin_elementwise_fma(a, b, c);
}
#else
__device__ __forceinline__ v2f fma2(v2f a, v2f b, v2f c) {
    v2f r; r.x = fmaf(a.x, b.x, c.x); r.y = fmaf(a.y, b.y, c.y); return r;
}
#endif

// ---------------------------------------------------------------------------
// Kernel 1 (fused): blocks 0..15  = embedding lookup + input projections
//                   blocks 16..78 = repack weight_o [16][32000] -> wo_p
//                                   [16000][16][2] (pair-packed per k)
// The two halves are independent; fusing saves one launch.
// ---------------------------------------------------------------------------
__global__ __launch_bounds__(256) void prep_kernel(
        const int* __restrict__ idx,
        const float* __restrict__ lookup,
        const float* __restrict__ wxf,
        const float* __restrict__ wxb,
        const float* __restrict__ bias_x,
        const float* __restrict__ bias_hf,
        const float* __restrict__ bias_hb,
        float* __restrict__ xpF, float* __restrict__ xpB,
        const float* __restrict__ wo, float* __restrict__ wo_p) {
    int blk = blockIdx.x;
    if (blk < 16) {
        int tok = blk * 256 + threadIdx.x;   // < 4096 == NROWS
        int e = idx[tok];
        const float* xr = lookup + (size_t)e * EMB;
        float x[EMB];
        #pragma unroll
        for (int i = 0; i < EMB; ++i) x[i] = xr[i];
        #pragma unroll
        for (int j = 0; j < HID; ++j) {
            float bx = bias_x[j];
            float fa = bx + bias_hf[j];
            float fb = bx + bias_hb[j];
            #pragma unroll
            for (int e2 = 0; e2 < EMB; ++e2) {
                float xv = x[e2];
                fa += xv * wxf[e2 * HID + j];
                fb += xv * wxb[e2 * HID + j];
            }
            xpF[(size_t)tok * HID + j] = fa;
            xpB[(size_t)tok * HID + j] = fb;
        }
    } else {
        int v2 = (blk - 16) * 256 + threadIdx.x;
        if (v2 >= VOCAB / 2) return;
        float2 buf[16];
        #pragma unroll
        for (int k = 0; k < 16; ++k)
            buf[k] = *reinterpret_cast<const float2*>(wo + (size_t)k * VOCAB + 2 * v2);
        float4* dst = reinterpret_cast<float4*>(wo_p + (size_t)v2 * 32);
        #pragma unroll
        for (int q = 0; q < 8; ++q)
            dst[q] = make_float4(buf[2 * q].x, buf[2 * q].y,
                                 buf[2 * q + 1].x, buf[2 * q + 1].y);
    }
}

// ---------------------------------------------------------------------------
// Kernel 2: the two Elman scans (sequential in S). 512 lanes over 8 blocks
// x 64 threads: gtid = dir*256 + b*8 + j. Store h BEFORE consuming x[s].
// Unchanged from previous round (inherently serial, ~12 us modeled).
// ---------------------------------------------------------------------------
__global__ __launch_bounds__(64) void scan_kernel(
        const float* __restrict__ xpF,
        const float* __restrict__ xpB,
        const float* __restrict__ whf,
        const float* __restrict__ whb,
        const float* __restrict__ Hf0,
        const float* __restrict__ Hb0,
        float* __restrict__ Hws) {
    int gtid = blockIdx.x * 64 + threadIdx.x;
    int j   = gtid & 7;
    int b   = (gtid >> 3) & 31;
    int dir = gtid >> 8;

    const float* wh = dir ? whb : whf;
    float w[HID];
    #pragma unroll
    for (int k = 0; k < HID; ++k) w[k] = wh[k * HID + j];

    const float* xp = dir ? xpB : xpF;
    float h = dir ? Hb0[j] : Hf0[j];

    int s0 = dir ? (S_LEN - 1) : 0;
    float xv = xp[(size_t)(s0 * B_SZ + b) * HID + j];

    for (int step = 0; step < S_LEN; ++step) {
        int s = dir ? (S_LEN - 1 - step) : step;
        int r = s * B_SZ + b;
        float xv_next = 0.0f;
        if (step + 1 < S_LEN) {
            int sn = dir ? (S_LEN - 2 - step) : (step + 1);
            xv_next = xp[(size_t)(sn * B_SZ + b) * HID + j];
        }
        Hws[(size_t)r * 16 + dir * HID + j] = h;   // store pre-update state
        float acc = xv;
        #pragma unroll
        for (int k = 0; k < HID; ++k)
            acc += __shfl(h, k, 8) * w[k];
        // tanh(x) = 1 - 2/(e^{2x}+1)
        float ex = __expf(2.0f * acc);
        h = 1.0f - 2.0f * __builtin_amdgcn_rcpf(ex + 1.0f);
        xv = xv_next;
    }
}

// ---------------------------------------------------------------------------
// Kernel 3 (pass A): partial sums of exp(logits). NOW 2 ROWS PER THREAD
// (r and r+2048): doubles FLOPs per scalar-loaded weight byte, halving the
// uniform-load traffic the 128-iter loop serializes on, and halves waves.
// Arithmetic order per row is unchanged -> Zpart bitwise identical.
// Zpart[chunk][row], 125 x 4096.
// ---------------------------------------------------------------------------
#define VCH_A 256
#define NCH_A (VOCAB / VCH_A)   // 125
__global__ __launch_bounds__(256) void passA_kernel(
        const float* __restrict__ Hws,
        const float* __restrict__ wo_p,
        const float* __restrict__ bias_o,
        float* __restrict__ Zpart) {
    int ra = blockIdx.y * 256 + threadIdx.x;      // 0..2047
    int rb = ra + (NROWS / 2);                    // 2048..4095
    int p0 = blockIdx.x * (VCH_A / 2);            // pair-index base

    float ha[16], hb[16];
    const float4* ha4 = reinterpret_cast<const float4*>(Hws + (size_t)ra * 16);
    const float4* hb4 = reinterpret_cast<const float4*>(Hws + (size_t)rb * 16);
    #pragma unroll
    for (int q = 0; q < 4; ++q) {
        float4 fa = ha4[q];
        float4 fb = hb4[q];
        ha[4 * q + 0] = fa.x; ha[4 * q + 1] = fa.y;
        ha[4 * q + 2] = fa.z; ha[4 * q + 3] = fa.w;
        hb[4 * q + 0] = fb.x; hb[4 * q + 1] = fb.y;
        hb[4 * q + 2] = fb.z; hb[4 * q + 3] = fb.w;
    }

    float za = 0.0f, zb = 0.0f;
    #pragma unroll 2
    for (int p = 0; p < VCH_A / 2; ++p) {
        const v2f* wp = reinterpret_cast<const v2f*>(wo_p + (size_t)(p0 + p) * 32);
        float2 bb = *reinterpret_cast<const float2*>(bias_o + (size_t)(p0 + p) * 2);
        v2f acca; acca.x = bb.x; acca.y = bb.y;
        v2f accb = acca;
        #pragma unroll
        for (int k = 0; k < 16; ++k) {
            v2f w = wp[k];
            v2f hka; hka.x = ha[k]; hka.y = ha[k];
            v2f hkb; hkb.x = hb[k]; hkb.y = hb[k];
            acca = fma2(hka, w, acca);
            accb = fma2(hkb, w, accb);
        }
        za += __expf(acca.x) + __expf(acca.y);
        zb += __expf(accb.x) + __expf(accb.y);
    }
    Zpart[(size_t)blockIdx.x * NROWS + ra] = za;
    Zpart[(size_t)blockIdx.x * NROWS + rb] = zb;
}

// ---------------------------------------------------------------------------
// Kernel 4: logZ[r] = log(sum over 125 chunk partials)
// ---------------------------------------------------------------------------
__global__ __launch_bounds__(256) void logz_kernel(
        const float* __restrict__ Zpart, float* __restrict__ logZ) {
    int r = blockIdx.x * blockDim.x + threadIdx.x;
    if (r >= NROWS) return;
    float s = 0.0f;
    for (int i = 0; i < NCH_A; ++i) s += Zpart[(size_t)i * NROWS + r];
    logZ[r] = logf(s);
}

// ---------------------------------------------------------------------------
// Kernel 5 (pass B): out[r][v] = logit - logZ[r].
// NEW: the 128-row Hws tile (8 KB) + logZ tile are staged into LDS once per
// block (cooperative float4 loads), replacing 129 per-row uniform s_load
// chains with broadcast ds_reads (uniform address -> conflict-free).
// Stores are nontemporal float4: the 524 MB stream must not evict wo from L2.
// ---------------------------------------------------------------------------
#define MT_B 128
__global__ __launch_bounds__(256) void passB_kernel(
        const float* __restrict__ Hws,
        const float* __restrict__ wo,
        const float* __restrict__ bias_o,
        const float* __restrict__ logZ,
        float* __restrict__ out) {
    __shared__ __attribute__((aligned(16))) float hsh[MT_B * 16];
    __shared__ float lz_sh[MT_B];
    int t = threadIdx.x;
    int r0 = blockIdx.y * MT_B;

    {
        const float4* src = reinterpret_cast<const float4*>(Hws + (size_t)r0 * 16);
        float4* dst = reinterpret_cast<float4*>(hsh);
        dst[t]       = src[t];        // 256 * 16 B = first 4 KB
        dst[t + 256] = src[t + 256];  // second 4 KB
        if (t < MT_B) lz_sh[t] = logZ[r0 + t];
    }
    __syncthreads();   // all threads reach this (guard comes after)

    int v = (blockIdx.x * 256 + t) * 4;
    if (v < VOCAB) {
        v2f w01[16], w23[16];
        #pragma unroll
        for (int k = 0; k < 16; ++k) {
            float4 w4 = *reinterpret_cast<const float4*>(wo + (size_t)k * VOCAB + v);
            w01[k].x = w4.x; w01[k].y = w4.y;
            w23[k].x = w4.z; w23[k].y = w4.w;
        }
        float4 bv = *reinterpret_cast<const float4*>(bias_o + v);
        v2f b01; b01.x = bv.x; b01.y = bv.y;
        v2f b23; b23.x = bv.z; b23.y = bv.w;

        #pragma unroll 2
        for (int rr = 0; rr < MT_B; ++rr) {
            const float* hr = hsh + rr * 16;           // broadcast ds_read
            v2f t01 = b01, t23 = b23;
            #pragma unroll
            for (int k = 0; k < 16; ++k) {
                float hk = hr[k];
                v2f hk2; hk2.x = hk; hk2.y = hk;
                t01 = fma2(hk2, w01[k], t01);
                t23 = fma2(hk2, w23[k], t23);
            }
            float lz = lz_sh[rr];
            v4f o;
            o.x = t01.x - lz; o.y = t01.y - lz;
            o.z = t23.x - lz; o.w = t23.y - lz;
            __builtin_nontemporal_store(
                o, reinterpret_cast<v4f*>(out + (size_t)(r0 + rr) * VOCAB + v));
        }
    }
}

// ---------------------------------------------------------------------------
extern "C" void kernel_launch(void* const* d_in, const int* in_sizes, int n_in,
                              void* d_out, int out_size, void* d_ws, size_t ws_size,
                              hipStream_t stream) {
    const int*   idx     = (const int*)d_in[0];
    const float* lookup  = (const float*)d_in[1];
    const float* wxf     = (const float*)d_in[2];
    const float* whf     = (const float*)d_in[3];
    const float* wxb     = (const float*)d_in[4];
    const float* whb     = (const float*)d_in[5];
    const float* wo      = (const float*)d_in[6];
    const float* Hf0     = (const float*)d_in[7];
    const float* Hb0     = (const float*)d_in[8];
    const float* bias_x  = (const float*)d_in[9];
    const float* bias_hf = (const float*)d_in[10];
    const float* bias_hb = (const float*)d_in[11];
    const float* bias_o  = (const float*)d_in[12];
    float* out = (float*)d_out;

    float* ws    = (float*)d_ws;
    float* xpF   = ws;                  //  32768 floats
    float* xpB   = ws + 32768;          //  32768
    float* Hws   = ws + 65536;          //  65536 (4096 x 16)
    float* wo_p  = ws + 131072;         // 512000 (16000 x 16 x 2)
    float* Zpart = ws + 643072;         // 512000 (125 x 4096)
    float* logZ  = ws + 1155072;        //   4096
    // total ~4.64 MB of ws

    prep_kernel<<<79, 256, 0, stream>>>(idx, lookup, wxf, wxb,
                                        bias_x, bias_hf, bias_hb,
                                        xpF, xpB, wo, wo_p);
    scan_kernel<<<8, 64, 0, stream>>>(xpF, xpB, whf, whb, Hf0, Hb0, Hws);
    passA_kernel<<<dim3(NCH_A, 8), 256, 0, stream>>>(Hws, wo_p, bias_o, Zpart);
    logz_kernel<<<16, 256, 0, stream>>>(Zpart, logZ);
    passB_kernel<<<dim3(32, NROWS / MT_B), 256, 0, stream>>>(Hws, wo, bias_o, logZ, out);
}